// Round 10
// baseline (798.984 us; speedup 1.0000x reference)
//
#include <hip/hip_runtime.h>
#include <hip/hip_bf16.h>

#define TWO_PI_F 6.2831853071795864769f

typedef __attribute__((ext_vector_type(8))) __bf16 bf16x8;
typedef __attribute__((ext_vector_type(4))) float f32x4;

__device__ __forceinline__ float bf2f_raw(unsigned short u) {
    return __uint_as_float(((unsigned int)u) << 16);
}
__device__ __forceinline__ unsigned short f2bf(float f) {
    unsigned int u = __float_as_uint(f);
    unsigned int r = (u + 0x7FFFu + ((u >> 16) & 1u)) >> 16;   // RNE
    return (unsigned short)r;
}
__device__ __forceinline__ float loadIn(const void* p, size_t i, bool f32) {
    return f32 ? ((const float*)p)[i] : bf2f_raw(((const unsigned short*)p)[i]);
}
// BN+act on a packed pair of bf16
__device__ __forceinline__ unsigned bn2u(unsigned u, float sa, float sb, float ha, float hb, float slope) {
    float fa = fmaf(bf2f_raw((unsigned short)(u & 0xffffu)), sa, ha);
    float fb = fmaf(bf2f_raw((unsigned short)(u >> 16)), sb, hb);
    fa = fa > 0.f ? fa : slope * fa;
    fb = fb > 0.f ? fb : slope * fb;
    return (unsigned)f2bf(fa) | ((unsigned)f2bf(fb) << 16);
}
__device__ __forceinline__ uint4 bn8(uint4 v, const float* sc, const float* sh, int c0, float slope) {
    float4 s0 = *(const float4*)(sc + c0), s1 = *(const float4*)(sc + c0 + 4);
    float4 h0 = *(const float4*)(sh + c0), h1 = *(const float4*)(sh + c0 + 4);
    v.x = bn2u(v.x, s0.x, s0.y, h0.x, h0.y, slope);
    v.y = bn2u(v.y, s0.z, s0.w, h0.z, h0.w, slope);
    v.z = bn2u(v.z, s1.x, s1.y, h1.x, h1.y, slope);
    v.w = bn2u(v.w, s1.z, s1.w, h1.z, h1.w, slope);
    return v;
}

// ---------------- ws layout ----------------
static constexpr size_t OFF_WC0 = 0;          // cod_w0 fp32 3072
static constexpr size_t OFF_WG2 = 3072;       // legacy slot (unused)
static constexpr size_t OFF_P   = 9216;
static constexpr size_t OFF_CB0 = OFF_P + 0;
static constexpr size_t OFF_CG0 = OFF_P + 64;
static constexpr size_t OFF_CBE0= OFF_P + 128;
static constexpr size_t OFF_CB1 = OFF_P + 192;
static constexpr size_t OFF_CG1 = OFF_P + 320;
static constexpr size_t OFF_CBE1= OFF_P + 448;
static constexpr size_t OFF_CB2 = OFF_P + 576;
static constexpr size_t OFF_GB0 = OFF_P + 640;
static constexpr size_t OFF_GG0 = OFF_P + 896;
static constexpr size_t OFF_GBE0= OFF_P + 1152;
static constexpr size_t OFF_GB1 = OFF_P + 1408;
static constexpr size_t OFF_GG1 = OFF_P + 1536;
static constexpr size_t OFF_GBE1= OFF_P + 1664;
static constexpr size_t OFF_GB2 = OFF_P + 1792;
static constexpr size_t OFF_SSUM  = OFF_P + 2048;   // 576
static constexpr size_t OFF_SSQ   = OFF_SSUM + 576;
static constexpr size_t OFF_SCALE = OFF_SSUM + 1152;
static constexpr size_t OFF_SHIFT = OFF_SCALE + 576;
static constexpr size_t OFF_K12   = OFF_SHIFT + 576;
static constexpr size_t OFF_FLAG  = OFF_K12 + 1024;
static constexpr size_t FP32_END  = OFF_FLAG + 16;   // floats
// ushort regions:
static constexpr size_t UXT = 2 * FP32_END;            // X region: X_s2d then X_t; 16777216
static constexpr size_t UYT = UXT + 16777216;          // Y region: Y_s2d head, then Y_t; 33554432
static constexpr size_t UZT = UYT + 8388608;           // Z_t (b,16,16,192) = 3145728
static constexpr size_t UW0 = UYT + 33554432;          // deconv0 pack 786432
static constexpr size_t UW1 = UW0 + 786432;            // deconv1 pack 524288
static constexpr size_t UWC1 = UW1 + 524288;           // conv1 pack 131072
static constexpr size_t UWC2 = UWC1 + 131072;          // conv2 pack 131072
static constexpr size_t UW2 = UWC2 + 131072;           // deconv2 pack 32768
static constexpr size_t WS_END_USHORT = UW2 + 32768;
static constexpr size_t WS_NEED_BYTES = WS_END_USHORT * 2;   // ~109.9 MB

// stat slots: L0:0(64) L1:64(128) G0:192(256) G1:448(128)

// ---------------- input dtype detection ----------------
__global__ void detect_kernel(const unsigned short* __restrict__ imgs, int* __restrict__ flag) {
    int t = threadIdx.x;  // 256
    unsigned short u = imgs[t];
    int e = (u >> 7) & 0xFF;
    unsigned long long b = __ballot(e >= 0xC0);
    __shared__ int cnt[4];
    if ((t & 63) == 0) cnt[t >> 6] = __popcll(b);
    __syncthreads();
    if (t == 0) flag[0] = (cnt[0] + cnt[1] + cnt[2] + cnt[3] >= 4) ? 1 : 0;
}

// ---------------- small param -> fp32 conversion ----------------
struct CvtJobs {
    const void* src[16];
    float* dst[16];
    int off[17];
};

__global__ void cvt_all_kernel(CvtJobs J, int total, const int* __restrict__ flg) {
    int i = blockIdx.x * 256 + threadIdx.x;
    if (i >= total) return;
    bool f32 = flg[0] != 0;
    int k = 0;
#pragma unroll
    for (int t = 0; t < 15; ++t) { if (i >= J.off[t + 1]) k = t + 1; }
    int r = i - J.off[k];
    J.dst[k][r] = loadIn(J.src[k], r, f32);
}

__global__ void zero_kernel(float* p, int n) {
    int i = blockIdx.x * 256 + threadIdx.x;
    if (i < n) p[i] = 0.f;
}

// ---------------- scatter packs (coalesced source reads) ----------------
// deconv weights, src layout (IC, OC, 4, 4)
__global__ void pack_w2_scatter(const void* __restrict__ src, unsigned short* __restrict__ dst,
                                int ICreal, int ICP, int OC, const int* __restrict__ flg) {
    bool f32 = flg[0] != 0;
    int s = blockIdx.x * 256 + threadIdx.x;
    int total = ICreal * OC * 16;
    if (s >= total) return;
    int ktap = s & 15;
    int t = s >> 4;
    int oc = t % OC;
    int ic = t / OC;
    int NK = ICP / 32, NOCT = OC / 64;
    int kc = ic >> 5, r5 = ic & 31, kq = r5 >> 3, jj = r5 & 7;
    int oct = oc >> 6, r6 = oc & 63, j = r6 >> 4, n = r6 & 15;
    int lane = kq * 16 + n;
    dst[((((size_t)(ktap * NOCT + oct) * NK + kc) * 4 + j) << 9) + lane * 8 + jj] =
        f2bf(loadIn(src, s, f32));
}

// conv weights, src layout (OC, IC, 4, 4)
__global__ void pack_wc_scatter(const void* __restrict__ src, unsigned short* __restrict__ dst,
                                int IC, int OC, const int* __restrict__ flg) {
    bool f32 = flg[0] != 0;
    int s = blockIdx.x * 256 + threadIdx.x;
    int total = IC * OC * 16;
    if (s >= total) return;
    int ktap = s & 15;
    int t = s >> 4;
    int ic = t % IC;
    int oc = t / IC;
    int NK = IC / 32, NOCT = OC / 64;
    int kc = ic >> 5, r5 = ic & 31, kq = r5 >> 3, jj = r5 & 7;
    int oct = oc >> 6, r6 = oc & 63, j = r6 >> 4, n = r6 & 15;
    int lane = kq * 16 + n;
    dst[((((size_t)(ktap * NOCT + oct) * NK + kc) * 4 + j) << 9) + lane * 8 + jj] =
        f2bf(loadIn(src, s, f32));
}

// deconv2 (small OC), src layout (IC, OCreal, 4, 4); dst[(ktap*NK+kc)*512 + lane*8 + jj], oc = n
__global__ void pack_w2s_scatter(const void* __restrict__ src, unsigned short* __restrict__ dst,
                                 int ICP, int OCreal, const int* __restrict__ flg) {
    bool f32 = flg[0] != 0;
    int s = blockIdx.x * 256 + threadIdx.x;
    int total = ICP * OCreal * 16;
    if (s >= total) return;
    int ktap = s & 15;
    int t = s >> 4;
    int oc = t % OCreal;
    int ic = t / OCreal;
    int NK = ICP / 32;
    int kc = ic >> 5, r5 = ic & 31, kq = r5 >> 3, jj = r5 & 7;
    int lane = kq * 16 + oc;
    dst[(size_t)(ktap * NK + kc) * 512 + lane * 8 + jj] = f2bf(loadIn(src, s, f32));
}

// ---------------- tiny MLP ----------------
__global__ void mlp_kernel(const void* __restrict__ Zg,
                           const void* __restrict__ lW, const void* __restrict__ lb,
                           const void* __restrict__ l1W, const void* __restrict__ l1b,
                           const void* __restrict__ l2W, const void* __restrict__ l2b,
                           float* __restrict__ K12, const int* __restrict__ flg) {
    bool f32 = flg[0] != 0;
    int b = blockIdx.x;
    int t = threadIdx.x;  // 64
    __shared__ float xs[64];
    float acc = loadIn(lb, t, f32);
    for (int c = 0; c < 64; ++c)
        acc += loadIn(Zg, (size_t)(b * 64 + c) * 256, f32) * loadIn(lW, t * 64 + c, f32);
    xs[t] = fmaxf(acc, 0.f);
    __syncthreads();
    if (t < 16) {
        int p = t & 7;
        const void* Wp = (t < 8) ? l1W : l2W;
        const void* bp = (t < 8) ? l1b : l2b;
        float a = loadIn(bp, p, f32);
        for (int h = 0; h < 64; ++h) a += xs[h] * loadIn(Wp, p * 64 + h, f32);
        K12[b * 16 + t] = a;
    }
}

// ---------------- conv0: imgs -> X_s2d, vector, +fused L0 stats ----------------
__global__ void conv0_s2d_kernel(const void* __restrict__ imgs, const float* __restrict__ w,
                                 const float* __restrict__ bias, unsigned short* __restrict__ xs,
                                 const int* __restrict__ flg,
                                 float* __restrict__ ssum, float* __restrict__ ssq) {
    bool f32 = flg[0] != 0;
    int b = blockIdx.z;
    int tile = blockIdx.x;
    int Y0 = (tile >> 2) * 16, X0 = (tile & 3) * 16;
    __shared__ float vin[3 * 34 * 35];
    __shared__ float wl[64 * 49];
    __shared__ float lss[64], lsq[64];
    if (threadIdx.x < 64) { lss[threadIdx.x] = 0.f; lsq[threadIdx.x] = 0.f; }
    for (int i = threadIdx.x; i < 3 * 34 * 34; i += 256) {
        int c = i % 34; int t = i / 34; int r = t % 34; int ic = t / 34;
        int iy = 2 * Y0 - 1 + r, ix = 2 * X0 - 1 + c;
        float v = 0.f;
        if (((unsigned)iy < 128u) & ((unsigned)ix < 128u))
            v = loadIn(imgs, ((size_t)(b * 3 + ic) * 128 + iy) * 128 + ix, f32);
        vin[(ic * 34 + r) * 35 + c] = v;
    }
    for (int i = threadIdx.x; i < 3072; i += 256) {
        int oc = i / 48, idx = i % 48;
        wl[oc * 49 + idx] = w[i];
    }
    __syncthreads();
    int q = threadIdx.x >> 2;
    int ocq = threadIdx.x & 3;
    int qy = q >> 3, qx = q & 7;
    float acc[4][16];
#pragma unroll
    for (int p = 0; p < 4; ++p)
#pragma unroll
        for (int o = 0; o < 16; ++o) acc[p][o] = 0.f;
    for (int ic = 0; ic < 3; ++ic) {
        float v[6][6];
#pragma unroll
        for (int r = 0; r < 6; ++r)
#pragma unroll
            for (int c = 0; c < 6; ++c)
                v[r][c] = vin[(ic * 34 + 4 * qy + r) * 35 + 4 * qx + c];
#pragma unroll
        for (int o = 0; o < 16; ++o) {
            const float* wo = wl + (ocq * 16 + o) * 49 + ic * 16;
#pragma unroll
            for (int ky = 0; ky < 4; ++ky)
#pragma unroll
                for (int kx = 0; kx < 4; ++kx) {
                    float wv = wo[ky * 4 + kx];
                    acc[0][o] = fmaf(v[ky][kx], wv, acc[0][o]);
                    acc[1][o] = fmaf(v[ky][kx + 2], wv, acc[1][o]);
                    acc[2][o] = fmaf(v[ky + 2][kx], wv, acc[2][o]);
                    acc[3][o] = fmaf(v[ky + 2][kx + 2], wv, acc[3][o]);
                }
        }
    }
    int j = (Y0 >> 1) + qy, i2 = (X0 >> 1) + qx;
    float s16[16], q16[16];
#pragma unroll
    for (int o = 0; o < 16; ++o) { s16[o] = 0.f; q16[o] = 0.f; }
#pragma unroll
    for (int p = 0; p < 4; ++p) {
        int dy = p >> 1, dx = p & 1;
        unsigned short tmp[16];
#pragma unroll
        for (int o = 0; o < 16; ++o) {
            float val = acc[p][o] + bias[ocq * 16 + o];
            tmp[o] = f2bf(val);
            s16[o] += val; q16[o] += val * val;
        }
        unsigned short* dst = xs + (((size_t)((b * 2 + dy) * 2 + dx) * 32 + j) * 32 + i2) * 64 + ocq * 16;
        *(uint4*)(dst) = *(const uint4*)(tmp);
        *(uint4*)(dst + 8) = *(const uint4*)(tmp + 8);
    }
#pragma unroll
    for (int o = 0; o < 16; ++o) {
        float s = s16[o], qq = q16[o];
        s += __shfl_down(s, 32); s += __shfl_down(s, 16); s += __shfl_down(s, 8); s += __shfl_down(s, 4);
        qq += __shfl_down(qq, 32); qq += __shfl_down(qq, 16); qq += __shfl_down(qq, 8); qq += __shfl_down(qq, 4);
        s16[o] = s; q16[o] = qq;
    }
    int lane = threadIdx.x & 63;
    if (lane < 4) {
#pragma unroll
        for (int o = 0; o < 16; ++o) {
            atomicAdd(&lss[lane * 16 + o], s16[o]);
            atomicAdd(&lsq[lane * 16 + o], q16[o]);
        }
    }
    __syncthreads();
    if (threadIdx.x < 64) {
        atomicAdd(&ssum[threadIdx.x], lss[threadIdx.x]);
        atomicAdd(&ssq[threadIdx.x], lsq[threadIdx.x]);
    }
}

// ---------------- conv1 (MFMA): X_s2d -> Y_s2d, fused BN-L0 on stage + L1 stats ----------------
__global__ void conv1_mfma_kernel(const unsigned short* __restrict__ xs,
                                  const unsigned short* __restrict__ wp,
                                  const float* __restrict__ bias,
                                  unsigned short* __restrict__ ys,
                                  const float* __restrict__ sc, const float* __restrict__ sh,
                                  float* __restrict__ ssum, float* __restrict__ ssq) {
    constexpr int STR = 72;
    __shared__ unsigned short lds[4 * 3 * 17 * STR];
    __shared__ float lss[128], lsq[128];
    int bid = blockIdx.x;
    int xt = bid & 1;
    int qp = (bid >> 1) & 15;
    int b = bid >> 5;
    int oy0 = qp * 2, x0 = xt * 16;
    if (threadIdx.x < 128) { lss[threadIdx.x] = 0.f; lsq[threadIdx.x] = 0.f; }
    for (int i = threadIdx.x; i < 1632; i += 256) {
        int icc = i & 7; int t = i >> 3;
        int col = t % 17; int rc = t / 17;
        int row = rc % 3; int pl = rc / 3;
        int py = pl >> 1, px = pl & 1;
        int j = oy0 - py + row;
        int ci = x0 - px + col;
        uint4 v = {0u, 0u, 0u, 0u};
        if (((unsigned)j < 32u) & ((unsigned)ci < 32u)) {
            v = *(const uint4*)(xs + ((size_t)((b * 4 + pl) * 32 + j) * 32 + ci) * 64 + icc * 8);
            v = bn8(v, sc, sh, icc * 8, 0.2f);
        }
        *(uint4*)(lds + ((pl * 3 + row) * 17 + col) * STR + icc * 8) = v;
    }
    __syncthreads();

    int wv = threadIdx.x >> 6, lane = threadIdx.x & 63;
    int r = wv >> 1, oct = wv & 1;
    int m = lane & 15, kq = lane >> 4;
    f32x4 acc[4];
#pragma unroll
    for (int j = 0; j < 4; ++j) acc[j] = (f32x4){0.f, 0.f, 0.f, 0.f};

#pragma unroll
    for (int ky = 0; ky < 4; ++ky) {
        int py = (ky & 1) ^ 1;
        int lrow = r + (ky >> 1);
#pragma unroll
        for (int kx = 0; kx < 4; ++kx) {
            int px = (kx & 1) ^ 1;
            int pl = py * 2 + px;
            int lcol = m + (kx >> 1);
            const unsigned short* lp = lds + ((pl * 3 + lrow) * 17 + lcol) * STR + kq * 8;
            int ktap = ky * 4 + kx;
            const unsigned short* bb = wp + (size_t)(ktap * 2 + oct) * 4096;
#pragma unroll
            for (int kc = 0; kc < 2; ++kc) {
                bf16x8 a = *(const bf16x8*)(lp + kc * 32);
                const unsigned short* bk = bb + kc * 2048 + lane * 8;
                bf16x8 b0 = *(const bf16x8*)(bk);
                bf16x8 b1 = *(const bf16x8*)(bk + 512);
                bf16x8 b2 = *(const bf16x8*)(bk + 1024);
                bf16x8 b3 = *(const bf16x8*)(bk + 1536);
                acc[0] = __builtin_amdgcn_mfma_f32_16x16x32_bf16(a, b0, acc[0], 0, 0, 0);
                acc[1] = __builtin_amdgcn_mfma_f32_16x16x32_bf16(a, b1, acc[1], 0, 0, 0);
                acc[2] = __builtin_amdgcn_mfma_f32_16x16x32_bf16(a, b2, acc[2], 0, 0, 0);
                acc[3] = __builtin_amdgcn_mfma_f32_16x16x32_bf16(a, b3, acc[3], 0, 0, 0);
            }
        }
    }
    int oy = oy0 + r;
    int pyo = oy & 1, jo = oy >> 1;
    int n = m;
    float bv[4] = {bias[oct * 64 + n], bias[oct * 64 + 16 + n],
                   bias[oct * 64 + 32 + n], bias[oct * 64 + 48 + n]};
    float sj[4] = {0.f, 0.f, 0.f, 0.f}, qj[4] = {0.f, 0.f, 0.f, 0.f};
#pragma unroll
    for (int reg = 0; reg < 4; ++reg) {
        int mm = kq * 4 + reg;
        int ox = x0 + mm;
        int pxo = ox & 1, io = ox >> 1;
        size_t base = (((size_t)((b * 2 + pyo) * 2 + pxo) * 16 + jo) * 16 + io) * 128 + oct * 64 + n;
#pragma unroll
        for (int j = 0; j < 4; ++j) {
            float val = acc[j][reg] + bv[j];
            ys[base + j * 16] = f2bf(val);
            sj[j] += val; qj[j] += val * val;
        }
    }
#pragma unroll
    for (int j = 0; j < 4; ++j) {
        sj[j] += __shfl_down(sj[j], 32); sj[j] += __shfl_down(sj[j], 16);
        qj[j] += __shfl_down(qj[j], 32); qj[j] += __shfl_down(qj[j], 16);
    }
    if (lane < 16) {
#pragma unroll
        for (int j = 0; j < 4; ++j) {
            atomicAdd(&lss[oct * 64 + j * 16 + lane], sj[j]);
            atomicAdd(&lsq[oct * 64 + j * 16 + lane], qj[j]);
        }
    }
    __syncthreads();
    if (threadIdx.x < 128) {
        atomicAdd(&ssum[threadIdx.x], lss[threadIdx.x]);
        atomicAdd(&ssq[threadIdx.x], lsq[threadIdx.x]);
    }
}

// ---------------- conv2 (MFMA) + tanh: Y_s2d -> Z_t[0:64), fused BN-L1 on stage ----------------
__global__ void conv2_mfma_kernel(const unsigned short* __restrict__ ys,
                                  const unsigned short* __restrict__ wp,
                                  const float* __restrict__ bias,
                                  unsigned short* __restrict__ zt,
                                  const float* __restrict__ sc, const float* __restrict__ sh) {
    constexpr int STR = 136;
    __shared__ unsigned short lds[4 * 3 * 17 * STR];
    int bid = blockIdx.x;
    int qp = bid & 7;
    int b = bid >> 3;
    int oy0 = qp * 2;
    for (int i = threadIdx.x; i < 3264; i += 256) {
        int icc = i & 15; int t = i >> 4;
        int col = t % 17; int rc = t / 17;
        int row = rc % 3; int pl = rc / 3;
        int py = pl >> 1, px = pl & 1;
        int j = oy0 - py + row;
        int ci = col - px;
        uint4 v = {0u, 0u, 0u, 0u};
        if (((unsigned)j < 16u) & ((unsigned)ci < 16u)) {
            v = *(const uint4*)(ys + ((size_t)((b * 4 + pl) * 16 + j) * 16 + ci) * 128 + icc * 8);
            v = bn8(v, sc, sh, icc * 8, 0.2f);
        }
        *(uint4*)(lds + ((pl * 3 + row) * 17 + col) * STR + icc * 8) = v;
    }
    __syncthreads();

    int wv = threadIdx.x >> 6, lane = threadIdx.x & 63;
    int r = wv >> 1, jh = wv & 1;
    int m = lane & 15, kq = lane >> 4;
    f32x4 acc[2];
    acc[0] = (f32x4){0.f, 0.f, 0.f, 0.f};
    acc[1] = acc[0];
#pragma unroll
    for (int ky = 0; ky < 4; ++ky) {
        int py = (ky & 1) ^ 1;
        int lrow = r + (ky >> 1);
#pragma unroll
        for (int kx = 0; kx < 4; ++kx) {
            int px = (kx & 1) ^ 1;
            int pl = py * 2 + px;
            int lcol = m + (kx >> 1);
            const unsigned short* lp = lds + ((pl * 3 + lrow) * 17 + lcol) * STR + kq * 8;
            int ktap = ky * 4 + kx;
            const unsigned short* bb = wp + (size_t)ktap * 8192;
#pragma unroll
            for (int kc = 0; kc < 4; ++kc) {
                bf16x8 a = *(const bf16x8*)(lp + kc * 32);
                const unsigned short* bk = bb + kc * 2048 + (jh * 2) * 512 + lane * 8;
                bf16x8 b0 = *(const bf16x8*)(bk);
                bf16x8 b1 = *(const bf16x8*)(bk + 512);
                acc[0] = __builtin_amdgcn_mfma_f32_16x16x32_bf16(a, b0, acc[0], 0, 0, 0);
                acc[1] = __builtin_amdgcn_mfma_f32_16x16x32_bf16(a, b1, acc[1], 0, 0, 0);
            }
        }
    }
    int oy = oy0 + r;
    int n = m;
    float bv0 = bias[(jh * 2) * 16 + n], bv1 = bias[(jh * 2 + 1) * 16 + n];
#pragma unroll
    for (int reg = 0; reg < 4; ++reg) {
        int x = kq * 4 + reg;
        size_t base = ((size_t)(b * 16 + oy) * 16 + x) * 192 + (jh * 2) * 16 + n;
        zt[base]      = f2bf(tanhf(acc[0][reg] + bv0));
        zt[base + 16] = f2bf(tanhf(acc[1][reg] + bv1));
    }
}

// ---------------- assemble Z_t[...][64:168) ----------------
__global__ void assemble_z(const void* __restrict__ Zl, const void* __restrict__ Zg,
                           const void* __restrict__ phi, const float* __restrict__ K12,
                           unsigned short* __restrict__ zt, const int* __restrict__ flg) {
    bool f32 = flg[0] != 0;
    int i = blockIdx.x * 256 + threadIdx.x;
    const int TOT = 64 * 104 * 256;
    if (i >= TOT) return;
    int pos = i & 255;
    int t = i >> 8;
    int c104 = t % 104;
    int b = t / 104;
    float val;
    if (c104 < 32) {
        val = loadIn(Zl, ((size_t)(b * 32 + c104) << 8) + pos, f32);
    } else if (c104 < 96) {
        val = loadIn(Zg, ((size_t)(b * 64 + (c104 - 32)) << 8) + pos, f32);
    } else {
        int p = c104 - 96;
        int y = pos >> 4, x = pos & 15;
        float k1 = K12[b * 16 + p];
        float k2 = K12[b * 16 + 8 + p];
        val = sinf(k1 * (float)y + k2 * (float)x + loadIn(phi, b * 8 + p, f32) * TWO_PI_F);
    }
    zt[((size_t)(b * 256 + pos)) * 192 + 64 + c104] = f2bf(val);
}

// ---------------- MFMA transposed-conv v3: QR=4 rows, optional fused-BN stage + fused stats ----------------
template <int ICP, int Q, int OC, bool APPLYBN, bool STATS>
__global__ void deconv_mfma3_kernel(const unsigned short* __restrict__ in_t,
                                    const unsigned short* __restrict__ wp2,
                                    const float* __restrict__ bias,
                                    unsigned short* __restrict__ out_t,
                                    const float* __restrict__ sc, const float* __restrict__ sh,
                                    float slope,
                                    float* __restrict__ ssum, float* __restrict__ ssq) {
    constexpr int QR = 4;
    constexpr int NOCT = OC / 64;
    constexpr int NK = ICP / 32;
    constexpr int XT = Q / 16;
    constexpr int NQB = Q / QR;
    constexpr int STRIDE = ICP + 8;
    constexpr int ROWS = QR + 2;
    __shared__ unsigned short lds[ROWS * 18 * STRIDE];
    __shared__ float lss[STATS ? OC : 1], lsq[STATS ? OC : 1];

    int bid = blockIdx.x;
    int xt = bid % XT;
    int t2 = bid / XT;
    int qp = t2 % NQB;
    int b = t2 / NQB;
    int qy0 = qp * QR;
    int x0 = xt * 16;

    if constexpr (STATS) {
        for (int c = threadIdx.x; c < OC; c += 256) { lss[c] = 0.f; lsq[c] = 0.f; }
    }

    constexpr int P8 = ICP / 8;
    constexpr int E8 = ROWS * 18 * P8;
    for (int i = threadIdx.x; i < E8; i += 256) {
        int icc = i % P8;
        int rc = i / P8;
        int row = rc / 18, col = rc % 18;
        int y = qy0 - 1 + row, x = x0 - 1 + col;
        uint4 val = {0u, 0u, 0u, 0u};
        if (((unsigned)y < (unsigned)Q) & ((unsigned)x < (unsigned)Q)) {
            val = *(const uint4*)(in_t + (size_t)((b * Q + y) * Q + x) * ICP + icc * 8);
            if constexpr (APPLYBN) val = bn8(val, sc, sh, icc * 8, slope);
        }
        *(uint4*)(lds + rc * STRIDE + icc * 8) = val;
    }
    __syncthreads();

    int wv = threadIdx.x >> 6, lane = threadIdx.x & 63;
    int dy = wv >> 1, dx = wv & 1;
    int m = lane & 15, kq = lane >> 4;

    for (int oct = 0; oct < NOCT; ++oct) {
        f32x4 acc[QR][4];
#pragma unroll
        for (int q = 0; q < QR; ++q)
#pragma unroll
            for (int j = 0; j < 4; ++j) acc[q][j] = (f32x4){0.f, 0.f, 0.f, 0.f};

#pragma unroll
        for (int t = 0; t < 4; ++t) {
            int rr = t >> 1, cc = t & 1;
            int ktap = ((3 - dy) - 2 * rr) * 4 + ((3 - dx) - 2 * cc);
            int col = m + dx + cc;
            int row0 = dy + rr;
            const unsigned short* bbase = wp2 + (size_t)((ktap * NOCT + oct) * NK) * 2048;
#pragma unroll
            for (int kc = 0; kc < NK; ++kc) {
                bf16x8 a[QR];
#pragma unroll
                for (int q = 0; q < QR; ++q)
                    a[q] = *(const bf16x8*)(lds + ((row0 + q) * 18 + col) * STRIDE + kc * 32 + kq * 8);
                bf16x8 b0 = *(const bf16x8*)(bbase + (kc * 4 + 0) * 512 + lane * 8);
                bf16x8 b1 = *(const bf16x8*)(bbase + (kc * 4 + 1) * 512 + lane * 8);
                bf16x8 b2 = *(const bf16x8*)(bbase + (kc * 4 + 2) * 512 + lane * 8);
                bf16x8 b3 = *(const bf16x8*)(bbase + (kc * 4 + 3) * 512 + lane * 8);
#pragma unroll
                for (int q = 0; q < QR; ++q) {
                    acc[q][0] = __builtin_amdgcn_mfma_f32_16x16x32_bf16(a[q], b0, acc[q][0], 0, 0, 0);
                    acc[q][1] = __builtin_amdgcn_mfma_f32_16x16x32_bf16(a[q], b1, acc[q][1], 0, 0, 0);
                    acc[q][2] = __builtin_amdgcn_mfma_f32_16x16x32_bf16(a[q], b2, acc[q][2], 0, 0, 0);
                    acc[q][3] = __builtin_amdgcn_mfma_f32_16x16x32_bf16(a[q], b3, acc[q][3], 0, 0, 0);
                }
            }
        }
        int n = m;
        float bv[4] = {bias[oct * 64 + n], bias[oct * 64 + 16 + n],
                       bias[oct * 64 + 32 + n], bias[oct * 64 + 48 + n]};
        float sj[4] = {0.f, 0.f, 0.f, 0.f}, qj[4] = {0.f, 0.f, 0.f, 0.f};
#pragma unroll
        for (int qyl = 0; qyl < QR; ++qyl) {
            int oy = 2 * (qy0 + qyl) + dy;
#pragma unroll
            for (int reg = 0; reg < 4; ++reg) {
                int mm = kq * 4 + reg;
                int ox = 2 * (x0 + mm) + dx;
                size_t base = ((size_t)((b * 2 * Q + oy) * (2 * Q) + ox)) * OC + oct * 64 + n;
#pragma unroll
                for (int j = 0; j < 4; ++j) {
                    float val = acc[qyl][j][reg] + bv[j];
                    out_t[base + j * 16] = f2bf(val);
                    if constexpr (STATS) { sj[j] += val; qj[j] += val * val; }
                }
            }
        }
        if constexpr (STATS) {
#pragma unroll
            for (int j = 0; j < 4; ++j) {
                sj[j] += __shfl_down(sj[j], 32); sj[j] += __shfl_down(sj[j], 16);
                qj[j] += __shfl_down(qj[j], 32); qj[j] += __shfl_down(qj[j], 16);
            }
            if (lane < 16) {
#pragma unroll
                for (int j = 0; j < 4; ++j) {
                    atomicAdd(&lss[oct * 64 + j * 16 + lane], sj[j]);
                    atomicAdd(&lsq[oct * 64 + j * 16 + lane], qj[j]);
                }
            }
        }
    }
    if constexpr (STATS) {
        __syncthreads();
        for (int c = threadIdx.x; c < OC; c += 256) {
            atomicAdd(&ssum[c], lss[c]);
            atomicAdd(&ssq[c], lsq[c]);
        }
    }
}

// ---------------- deconv2 (MFMA, OC 3->16) + tanh -> fp32 NCHW, fused BN-G1 stage, QR=4 ----------------
__global__ void deconv2_mfma_kernel(const unsigned short* __restrict__ yt,
                                    const unsigned short* __restrict__ wp,
                                    const float* __restrict__ bias,
                                    float* __restrict__ outp,
                                    const float* __restrict__ sc, const float* __restrict__ sh) {
    constexpr int Q = 64, ICP = 128, NK = 4, STRIDE = 136, QR = 4, ROWS = 6;
    __shared__ unsigned short lds[ROWS * 18 * STRIDE];
    int bid = blockIdx.x;
    int xt = bid & 3;
    int t2 = bid >> 2;
    int qp = t2 & 15;
    int b = t2 >> 4;
    int qy0 = qp * QR, x0 = xt * 16;

    for (int i = threadIdx.x; i < ROWS * 18 * 16; i += 256) {
        int icc = i & 15;
        int rc = i >> 4;
        int row = rc / 18, col = rc % 18;
        int y = qy0 - 1 + row, x = x0 - 1 + col;
        uint4 v = {0u, 0u, 0u, 0u};
        if (((unsigned)y < (unsigned)Q) & ((unsigned)x < (unsigned)Q)) {
            v = *(const uint4*)(yt + (size_t)((b * Q + y) * Q + x) * ICP + icc * 8);
            v = bn8(v, sc, sh, icc * 8, 0.f);
        }
        *(uint4*)(lds + rc * STRIDE + icc * 8) = v;
    }
    __syncthreads();

    int wv = threadIdx.x >> 6, lane = threadIdx.x & 63;
    int dy = wv >> 1, dx = wv & 1;
    int m = lane & 15, kq = lane >> 4;
    f32x4 acc[QR];
#pragma unroll
    for (int q = 0; q < QR; ++q) acc[q] = (f32x4){0.f, 0.f, 0.f, 0.f};

#pragma unroll
    for (int t = 0; t < 4; ++t) {
        int rr = t >> 1, cc = t & 1;
        int ktap = ((3 - dy) - 2 * rr) * 4 + ((3 - dx) - 2 * cc);
        int col = m + dx + cc;
        int row0 = dy + rr;
        const unsigned short* bb = wp + (size_t)(ktap * NK) * 512;
#pragma unroll
        for (int kc = 0; kc < NK; ++kc) {
            bf16x8 b0 = *(const bf16x8*)(bb + kc * 512 + lane * 8);
#pragma unroll
            for (int q = 0; q < QR; ++q) {
                bf16x8 a = *(const bf16x8*)(lds + ((row0 + q) * 18 + col) * STRIDE + kc * 32 + kq * 8);
                acc[q] = __builtin_amdgcn_mfma_f32_16x16x32_bf16(a, b0, acc[q], 0, 0, 0);
            }
        }
    }
    int n = m;
    if (n < 3) {
        float bv = bias[n];
        size_t ob = (size_t)(b * 3 + n) * 16384;
#pragma unroll
        for (int q = 0; q < QR; ++q) {
            int oy = 2 * (qy0 + q) + dy;
#pragma unroll
            for (int reg = 0; reg < 4; ++reg) {
                int mm = kq * 4 + reg;
                int ox = 2 * (x0 + mm) + dx;
                outp[ob + (size_t)oy * 128 + ox] = tanhf(acc[q][reg] + bv);
            }
        }
    }
}

// ---------------- BN finalize ----------------
__global__ void bn_fin_kernel(const float* __restrict__ ssum, const float* __restrict__ ssq,
                              const float* __restrict__ g, const float* __restrict__ be,
                              float* __restrict__ scale, float* __restrict__ shift,
                              int statoff, int C, float invN) {
    int c = threadIdx.x;
    if (c >= C) return;
    float m = ssum[statoff + c] * invN;
    float v = ssq[statoff + c] * invN - m * m;
    v = fmaxf(v, 0.f);
    float sc = g[c] * rsqrtf(v + 1e-5f);
    scale[statoff + c] = sc;
    shift[statoff + c] = be[c] - m * sc;
}

extern "C" void kernel_launch(void* const* d_in, const int* in_sizes, int n_in,
                              void* d_out, int out_size, void* d_ws, size_t ws_size,
                              hipStream_t stream) {
    if (ws_size < WS_NEED_BYTES) {
        hipMemsetAsync(d_out, 0, (size_t)out_size * 4, stream);
        return;
    }

    float* W = (float*)d_ws;
    unsigned short* U = (unsigned short*)d_ws;
    int* FLG = (int*)(W + OFF_FLAG);

    detect_kernel<<<1, 256, 0, stream>>>((const unsigned short*)d_in[2], FLG);

    // small fp32 conversions: cod_w0 + all bias/gamma/beta
    CvtJobs J;
    const int srcIdx[15] = {10, 11, 12, 13, 15, 16, 17, 19, 21, 22, 23, 25, 26, 27, 29};
    const int cnt[15]    = {3072, 64, 64, 64, 128, 128, 128, 64, 256, 256, 256, 128, 128, 128, 3};
    float* dsts[15] = {W + OFF_WC0,
                       W + OFF_CB0, W + OFF_CG0, W + OFF_CBE0, W + OFF_CB1, W + OFF_CG1, W + OFF_CBE1,
                       W + OFF_CB2, W + OFF_GB0, W + OFF_GG0, W + OFF_GBE0, W + OFF_GB1, W + OFF_GG1,
                       W + OFF_GBE1, W + OFF_GB2};
    int off = 0;
    for (int k = 0; k < 15; ++k) {
        J.src[k] = d_in[srcIdx[k]];
        J.dst[k] = dsts[k];
        J.off[k] = off;
        off += cnt[k];
    }
    J.off[15] = off;
    J.off[16] = off;
    cvt_all_kernel<<<(off + 255) / 256, 256, 0, stream>>>(J, off, FLG);

    zero_kernel<<<5, 256, 0, stream>>>(W + OFF_SSUM, 1152);
    zero_kernel<<<6144, 256, 0, stream>>>((float*)(U + UZT), 1572864);   // Z_t incl. pad ch
    zero_kernel<<<1536, 256, 0, stream>>>((float*)(U + UW0), 393216);    // deconv0 pack pad
    zero_kernel<<<64, 256, 0, stream>>>((float*)(U + UW2), 16384);       // deconv2 pack pad

    // weight packs (coalesced reads, scattered writes)
    pack_w2_scatter<<<2688, 256, 0, stream>>>(d_in[20], U + UW0, 168, 192, 256, FLG);
    pack_w2_scatter<<<2048, 256, 0, stream>>>(d_in[24], U + UW1, 256, 256, 128, FLG);
    pack_wc_scatter<<<512, 256, 0, stream>>>(d_in[14], U + UWC1, 64, 128, FLG);
    pack_wc_scatter<<<512, 256, 0, stream>>>(d_in[18], U + UWC2, 128, 64, FLG);
    pack_w2s_scatter<<<24, 256, 0, stream>>>(d_in[28], U + UW2, 128, 3, FLG);

    mlp_kernel<<<64, 64, 0, stream>>>(d_in[1], d_in[4], d_in[5], d_in[6], d_in[7],
                                      d_in[8], d_in[9], W + OFF_K12, FLG);

    // ---- conv0 -> X_s2d (+L0 stats) ----
    conv0_s2d_kernel<<<dim3(16, 1, 64), 256, 0, stream>>>(
        d_in[2], W + OFF_WC0, W + OFF_CB0, U + UXT, FLG,
        W + OFF_SSUM + 0, W + OFF_SSQ + 0);
    bn_fin_kernel<<<1, 256, 0, stream>>>(W + OFF_SSUM, W + OFF_SSQ, W + OFF_CG0, W + OFF_CBE0,
                                         W + OFF_SCALE, W + OFF_SHIFT, 0, 64, 1.f / 262144.f);

    // ---- conv1 (BN-L0 fused, +L1 stats) -> Y_s2d ----
    conv1_mfma_kernel<<<2048, 256, 0, stream>>>(
        U + UXT, U + UWC1, W + OFF_CB1, U + UYT,
        W + OFF_SCALE + 0, W + OFF_SHIFT + 0,
        W + OFF_SSUM + 64, W + OFF_SSQ + 64);
    bn_fin_kernel<<<1, 256, 0, stream>>>(W + OFF_SSUM, W + OFF_SSQ, W + OFF_CG1, W + OFF_CBE1,
                                         W + OFF_SCALE, W + OFF_SHIFT, 64, 128, 1.f / 65536.f);

    // ---- conv2 (BN-L1 fused) + tanh -> Z_t[0:64) ----
    conv2_mfma_kernel<<<512, 256, 0, stream>>>(
        U + UYT, U + UWC2, W + OFF_CB2, U + UZT,
        W + OFF_SCALE + 64, W + OFF_SHIFT + 64);

    // ---- Z_t[64:168) ----
    assemble_z<<<6656, 256, 0, stream>>>(d_in[0], d_in[1], d_in[3], W + OFF_K12, U + UZT, FLG);

    // ---- gen deconv0 (no BN in, +G0 stats): Z_t -> X_t(32,32,256) ----
    deconv_mfma3_kernel<192, 16, 256, false, true><<<256, 256, 0, stream>>>(
        U + UZT, U + UW0, W + OFF_GB0, U + UXT,
        nullptr, nullptr, 0.f,
        W + OFF_SSUM + 192, W + OFF_SSQ + 192);
    bn_fin_kernel<<<1, 256, 0, stream>>>(W + OFF_SSUM, W + OFF_SSQ, W + OFF_GG0, W + OFF_GBE0,
                                         W + OFF_SCALE, W + OFF_SHIFT, 192, 256, 1.f / 65536.f);

    // ---- gen deconv1 (BN-G0 fused, +G1 stats): X_t -> Y_t(64,64,128) ----
    deconv_mfma3_kernel<256, 32, 128, true, true><<<1024, 256, 0, stream>>>(
        U + UXT, U + UW1, W + OFF_GB1, U + UYT,
        W + OFF_SCALE + 192, W + OFF_SHIFT + 192, 0.f,
        W + OFF_SSUM + 448, W + OFF_SSQ + 448);
    bn_fin_kernel<<<1, 256, 0, stream>>>(W + OFF_SSUM, W + OFF_SSQ, W + OFF_GG1, W + OFF_GBE1,
                                         W + OFF_SCALE, W + OFF_SHIFT, 448, 128, 1.f / 262144.f);

    // ---- gen deconv2 (BN-G1 fused) + tanh -> d_out fp32 ----
    deconv2_mfma_kernel<<<4096, 256, 0, stream>>>(
        U + UYT, U + UW2, W + OFF_GB2, (float*)d_out,
        W + OFF_SCALE + 448, W + OFF_SHIFT + 448);
}